// Round 10
// baseline (115.874 us; speedup 1.0000x reference)
//
#include <hip/hip_runtime.h>
#include <float.h>

// VectorQuantizer on MI355X — bit-exact numpy-f32 replication (R4-proven numerics).
//
// Ladder: R4 274us -> R7 97us (s_load e-rows, 4 waves/SIMD). R7-R9 lesson: the
// allocator ALWAYS remats xv loads from read-only memory (VGPR stayed 56/60/32
// across launch_bounds/waves_per_eu/LDS attempts); pinning spills (R6, 5.5ms),
// LDS staging oversubscribes the per-CU LDS pipe (R9, 109us).
// R10: make the remat CHEAP instead of fighting it — pre-transpose x to
// contiguous xt[n][64] (one streaming kernel, ~32MB, also computes t1 with the
// exact np tree). k-loop remat becomes 16 dwordx4 with imm offsets off one base
// (vs 64 strided scalars + 64-bit addr arith); block's xt slice is L1-resident.
// Fallback to the R7 path if ws_size < 17MB.
#pragma clang fp contract(off)

#define K_EMB   512
#define D_EMB   64
#define N_PIX   65536
#define Q_ELEMS 4194304   // 64 * 64 * 32 * 32
#define NBLK    1024      // vq_main grid: 64 pixels per block, 4 waves split K

// ws layout (floats): [t2 512][partial 1024][xt 4194304][t1a 65536]
#define WS_NEED ((size_t)(512 + 1024 + Q_ELEMS + N_PIX) * 4)

// numpy pairwise_sum order for n=64 contiguous f32, summing PRE-ROUNDED squares.
__device__ __forceinline__ float np_sumsq64(const float* __restrict__ v) {
    float r[8];
    #pragma unroll
    for (int j = 0; j < 8; ++j) r[j] = v[j] * v[j];
    #pragma unroll
    for (int i = 8; i < 64; i += 8) {
        #pragma unroll
        for (int j = 0; j < 8; ++j) {
            float s = v[i + j] * v[i + j];
            r[j] = r[j] + s;
        }
    }
    return ((r[0] + r[1]) + (r[2] + r[3])) + ((r[4] + r[5]) + (r[6] + r[7]));
}

// ---------------- kernel 0: transpose x -> xt[n][64], compute t1 ----------------
__global__ __launch_bounds__(256) void vq_xt(const float* __restrict__ x,
                                             float* __restrict__ xt,
                                             float* __restrict__ t1a) {
    const int n  = blockIdx.x * 256 + threadIdx.x;
    const int b  = n >> 10;
    const int hw = n & 1023;
    const float* __restrict__ xp = x + b * 65536 + hw;
    float* __restrict__ xr = xt + (size_t)n * 64;

    float r[8];
    #pragma unroll
    for (int i = 0; i < 8; ++i) {
        float v0 = xp[(8 * i + 0) * 1024];
        float v1 = xp[(8 * i + 1) * 1024];
        float v2 = xp[(8 * i + 2) * 1024];
        float v3 = xp[(8 * i + 3) * 1024];
        float v4 = xp[(8 * i + 4) * 1024];
        float v5 = xp[(8 * i + 5) * 1024];
        float v6 = xp[(8 * i + 6) * 1024];
        float v7 = xp[(8 * i + 7) * 1024];
        if (i == 0) {
            r[0] = v0 * v0; r[1] = v1 * v1; r[2] = v2 * v2; r[3] = v3 * v3;
            r[4] = v4 * v4; r[5] = v5 * v5; r[6] = v6 * v6; r[7] = v7 * v7;
        } else {
            float s;
            s = v0 * v0; r[0] = r[0] + s;
            s = v1 * v1; r[1] = r[1] + s;
            s = v2 * v2; r[2] = r[2] + s;
            s = v3 * v3; r[3] = r[3] + s;
            s = v4 * v4; r[4] = r[4] + s;
            s = v5 * v5; r[5] = r[5] + s;
            s = v6 * v6; r[6] = r[6] + s;
            s = v7 * v7; r[7] = r[7] + s;
        }
        ((float4*)(xr + 8 * i))[0] = make_float4(v0, v1, v2, v3);
        ((float4*)(xr + 8 * i))[1] = make_float4(v4, v5, v6, v7);
    }
    t1a[n] = ((r[0] + r[1]) + (r[2] + r[3])) + ((r[4] + r[5]) + (r[6] + r[7]));
}

// ---------------- kernel 1: t2[k] = np-f32 sum(emb_k^2) ----------------
__global__ __launch_bounds__(256) void vq_prep(const float* __restrict__ emb,
                                               float* __restrict__ t2) {
    int k = blockIdx.x * 256 + threadIdx.x;
    if (k < K_EMB) {
        const float* ep = emb + (k << 6);
        float e[D_EMB];
        #pragma unroll
        for (int j = 0; j < D_EMB; ++j) e[j] = ep[j];
        t2[k] = np_sumsq64(e);
    }
}

// ---------------- kernel 2: main VQ (CONTIG: read xt; else read x strided) ----
template <bool CONTIG>
__global__ __launch_bounds__(256) void vq_main(const float* __restrict__ x,
                                               const float* __restrict__ xt,
                                               const float* __restrict__ t1a,
                                               const float* __restrict__ emb,
                                               const float* __restrict__ t2,
                                               float* __restrict__ out_q,
                                               float* __restrict__ out_idx,
                                               float* __restrict__ partial) {
    const int tid  = threadIdx.x;
    const int lane = tid & 63;
    // PROVABLY wave-uniform wave id -> e addresses stay scalar -> s_load (R7)
    const int wave = __builtin_amdgcn_readfirstlane(tid >> 6);

    const int n  = blockIdx.x * 64 + lane;           // pixel index
    const int b  = n >> 10;
    const int hw = n & 1023;

    const float* __restrict__ xp = CONTIG ? (xt + (size_t)n * 64)
                                          : (x + b * 65536 + hw);

    float xv[D_EMB];
    #pragma unroll
    for (int d = 0; d < D_EMB; ++d) xv[d] = CONTIG ? xp[d] : xp[d * 1024];

    const float t1 = CONTIG ? t1a[n] : np_sumsq64(xv);

    float best = FLT_MAX;
    int   bi   = 0;
    const int k0 = wave << 7;          // this wave's 128-code range (uniform)
    for (int kk = 0; kk < 128; kk += 4) {
        const int k = k0 + kk;
        const float* __restrict__ e0 = emb + ((k + 0) << 6);  // uniform -> s_load
        const float* __restrict__ e1 = emb + ((k + 1) << 6);
        const float* __restrict__ e2 = emb + ((k + 2) << 6);
        const float* __restrict__ e3 = emb + ((k + 3) << 6);
        float a0 = 0.f, a1 = 0.f, a2 = 0.f, a3 = 0.f;
        #pragma unroll
        for (int d = 0; d < D_EMB; ++d) {
            a0 = fmaf(xv[d], e0[d], a0);   // BLAS chain: one fma rounding per step
            a1 = fmaf(xv[d], e1[d], a1);
            a2 = fmaf(xv[d], e2[d], a2);
            a3 = fmaf(xv[d], e3[d], a3);
        }
        // dist = fl32( fl32(t1+t2) - 2*d ): 2*d exact -> fmaf = identical rounding
        float X0 = t1 + t2[k + 0];
        float X1 = t1 + t2[k + 1];
        float X2 = t1 + t2[k + 2];
        float X3 = t1 + t2[k + 3];
        float d0 = fmaf(-2.f, a0, X0);
        float d1 = fmaf(-2.f, a1, X1);
        float d2 = fmaf(-2.f, a2, X2);
        float d3 = fmaf(-2.f, a3, X3);
        if (d0 < best) { best = d0; bi = k + 0; }   // strict <: first-min tiebreak
        if (d1 < best) { best = d1; bi = k + 1; }
        if (d2 < best) { best = d2; bi = k + 2; }
        if (d3 < best) { best = d3; bi = k + 3; }
    }

    // cross-wave argmin merge (ascending wave == ascending k; strict <)
    __shared__ float s_best[4][64];
    __shared__ int   s_bi[4][64];
    s_best[wave][lane] = best;
    s_bi[wave][lane]   = bi;
    __syncthreads();
    if (wave != 0) return;

    #pragma unroll
    for (int w = 1; w < 4; ++w) {
        float dw = s_best[w][lane];
        if (dw < best) { best = dw; bi = s_bi[w][lane]; }
    }

    // epilogue (wave 0): gather winning embedding, write quantized, loss partial
    const float4* __restrict__ eq = (const float4*)(emb + (bi << 6));
    float* __restrict__ qp = out_q + b * 65536 + hw;
    float acc = 0.f;
    #pragma unroll
    for (int j = 0; j < 16; ++j) {
        float4 q = eq[j];
        const int d = j * 4;
        float f0 = q.x - xv[d + 0];
        float f1 = q.y - xv[d + 1];
        float f2 = q.z - xv[d + 2];
        float f3 = q.w - xv[d + 3];
        acc = fmaf(f0, f0, acc);
        acc = fmaf(f1, f1, acc);
        acc = fmaf(f2, f2, acc);
        acc = fmaf(f3, f3, acc);
        qp[(d + 0) * 1024] = q.x;
        qp[(d + 1) * 1024] = q.y;
        qp[(d + 2) * 1024] = q.z;
        qp[(d + 3) * 1024] = q.w;
    }
    out_idx[n] = (float)bi;

    // wave-internal loss reduce
    #pragma unroll
    for (int off = 32; off > 0; off >>= 1) acc += __shfl_down(acc, off);
    if (lane == 0) partial[blockIdx.x] = acc;
}

// ---------------- kernel 3: finalize loss over 1024 partials ----------------
__global__ __launch_bounds__(256) void vq_loss(const float* __restrict__ partial,
                                               float* __restrict__ loss) {
    const int t = threadIdx.x;
    float v = (partial[t] + partial[t + 256]) + (partial[t + 512] + partial[t + 768]);
    #pragma unroll
    for (int off = 32; off > 0; off >>= 1) v += __shfl_down(v, off);
    __shared__ float red[4];
    if ((t & 63) == 0) red[t >> 6] = v;
    __syncthreads();
    if (t == 0)
        loss[0] = 1.25f * ((red[0] + red[1]) + (red[2] + red[3])) / (float)Q_ELEMS;
}

extern "C" void kernel_launch(void* const* d_in, const int* in_sizes, int n_in,
                              void* d_out, int out_size, void* d_ws, size_t ws_size,
                              hipStream_t stream) {
    const float* x   = (const float*)d_in[0];   // [64,64,32,32] NCHW
    const float* emb = (const float*)d_in[1];   // [512,64]

    float* out_q    = (float*)d_out;                // [4194304]
    float* out_loss = (float*)d_out + Q_ELEMS;      // [1]
    float* out_idx  = (float*)d_out + Q_ELEMS + 1;  // [65536] as float

    float* t2      = (float*)d_ws;                  // 512
    float* partial = t2 + K_EMB;                    // 1024
    float* xt      = partial + 1024;                // 4194304 (16B-aligned: 6144B off)
    float* t1a     = xt + Q_ELEMS;                  // 65536

    vq_prep<<<2, 256, 0, stream>>>(emb, t2);
    if (ws_size >= WS_NEED) {
        vq_xt<<<256, 256, 0, stream>>>(x, xt, t1a);
        vq_main<true><<<NBLK, 256, 0, stream>>>(x, xt, t1a, emb, t2,
                                                out_q, out_idx, partial);
    } else {
        vq_main<false><<<NBLK, 256, 0, stream>>>(x, x, x, emb, t2,
                                                 out_q, out_idx, partial);
    }
    vq_loss<<<1, 256, 0, stream>>>(partial, out_loss);
}

// Round 11
// 105.421 us; speedup vs baseline: 1.0991x; 1.0991x over previous
//
#include <hip/hip_runtime.h>
#include <float.h>

// VectorQuantizer on MI355X — bit-exact numpy-f32 replication (R4-proven numerics).
//
// Ladder: R4 274us (1 wave/SIMD) -> R7 97us (s_load e-rows + 4 waves/SIMD).
// R9 (x in LDS): LDS-pipe oversubscription, 109us. R10 (contiguous xt): vq_main
// IDENTICAL 96us -> xv access pattern irrelevant; invariant is VALU busy ~60us
// at 62% duty. Diagnosis: per-k-group s_load/lgkmcnt waits; 4 waves/SIMD can't
// fill them (occupancy curve 1->4 waves gave VALUBusy 22->62%, saturating).
// R11: 1024-thread blocks, 16-way in-block K-split (wave w scans 32 codes),
// 2 blocks/CU resident -> 8 waves/SIMD. In-block LDS argmin merge, ascending
// wave == ascending k, strict '<' -> bit-identical idx. xt kernel dropped.
#pragma clang fp contract(off)

#define K_EMB   512
#define D_EMB   64
#define Q_ELEMS 4194304   // 64 * 64 * 32 * 32
#define NBLK    1024      // 64 pixels per block, 16 waves split K

// numpy pairwise_sum order for n=64 contiguous f32, summing PRE-ROUNDED squares.
__device__ __forceinline__ float np_sumsq64(const float* __restrict__ v) {
    float r[8];
    #pragma unroll
    for (int j = 0; j < 8; ++j) r[j] = v[j] * v[j];
    #pragma unroll
    for (int i = 8; i < 64; i += 8) {
        #pragma unroll
        for (int j = 0; j < 8; ++j) {
            float s = v[i + j] * v[i + j];
            r[j] = r[j] + s;
        }
    }
    return ((r[0] + r[1]) + (r[2] + r[3])) + ((r[4] + r[5]) + (r[6] + r[7]));
}

// ---------------- kernel 1: t2[k] = np-f32 sum(emb_k^2) ----------------
__global__ __launch_bounds__(256) void vq_prep(const float* __restrict__ emb,
                                               float* __restrict__ t2) {
    int k = blockIdx.x * 256 + threadIdx.x;
    if (k < K_EMB) {
        const float* ep = emb + (k << 6);
        float e[D_EMB];
        #pragma unroll
        for (int j = 0; j < D_EMB; ++j) e[j] = ep[j];
        t2[k] = np_sumsq64(e);
    }
}

// ---------------- kernel 2: main VQ ----------------
__global__ __launch_bounds__(1024) void vq_main(const float* __restrict__ x,
                                                const float* __restrict__ emb,
                                                const float* __restrict__ t2,
                                                float* __restrict__ out_q,
                                                float* __restrict__ out_idx,
                                                float* __restrict__ partial) {
    const int tid  = threadIdx.x;
    const int lane = tid & 63;
    // PROVABLY wave-uniform wave id -> e addresses stay scalar -> s_load (R7)
    const int wave = __builtin_amdgcn_readfirstlane(tid >> 6);   // 0..15

    const int n  = blockIdx.x * 64 + lane;           // pixel index
    const int b  = n >> 10;
    const int hw = n & 1023;
    const float* __restrict__ xp = x + b * 65536 + hw;

    // x[n, 0..63]; allocator remats these in the k-loop (proven harmless R10)
    float xv[D_EMB];
    #pragma unroll
    for (int d = 0; d < D_EMB; ++d) xv[d] = xp[d * 1024];

    const float t1 = np_sumsq64(xv);   // numpy tree, f32 (same in all 16 waves)

    float best = FLT_MAX;
    int   bi   = 0;
    const int k0 = wave << 5;          // this wave's 32-code range (uniform)
    for (int kk = 0; kk < 32; kk += 4) {
        const int k = k0 + kk;
        const float* __restrict__ e0 = emb + ((k + 0) << 6);  // uniform -> s_load
        const float* __restrict__ e1 = emb + ((k + 1) << 6);
        const float* __restrict__ e2 = emb + ((k + 2) << 6);
        const float* __restrict__ e3 = emb + ((k + 3) << 6);
        float a0 = 0.f, a1 = 0.f, a2 = 0.f, a3 = 0.f;
        #pragma unroll
        for (int d = 0; d < D_EMB; ++d) {
            a0 = fmaf(xv[d], e0[d], a0);   // BLAS chain: one fma rounding per step
            a1 = fmaf(xv[d], e1[d], a1);
            a2 = fmaf(xv[d], e2[d], a2);
            a3 = fmaf(xv[d], e3[d], a3);
        }
        // dist = fl32( fl32(t1+t2) - 2*d ): 2*d exact -> fmaf = identical rounding
        float X0 = t1 + t2[k + 0];
        float X1 = t1 + t2[k + 1];
        float X2 = t1 + t2[k + 2];
        float X3 = t1 + t2[k + 3];
        float d0 = fmaf(-2.f, a0, X0);
        float d1 = fmaf(-2.f, a1, X1);
        float d2 = fmaf(-2.f, a2, X2);
        float d3 = fmaf(-2.f, a3, X3);
        if (d0 < best) { best = d0; bi = k + 0; }   // strict <: first-min tiebreak
        if (d1 < best) { best = d1; bi = k + 1; }
        if (d2 < best) { best = d2; bi = k + 2; }
        if (d3 < best) { best = d3; bi = k + 3; }
    }

    // cross-wave argmin merge (ascending wave == ascending k; strict <)
    __shared__ float s_best[16][64];
    __shared__ int   s_bi[16][64];
    s_best[wave][lane] = best;
    s_bi[wave][lane]   = bi;
    __syncthreads();
    if (wave != 0) return;

    #pragma unroll
    for (int w = 1; w < 16; ++w) {
        float dw = s_best[w][lane];
        if (dw < best) { best = dw; bi = s_bi[w][lane]; }
    }

    // epilogue (wave 0): gather winning embedding, write quantized, loss partial
    const float4* __restrict__ eq = (const float4*)(emb + (bi << 6));
    float* __restrict__ qp = out_q + b * 65536 + hw;
    float acc = 0.f;
    #pragma unroll
    for (int j = 0; j < 16; ++j) {
        float4 q = eq[j];
        const int d = j * 4;
        float f0 = q.x - xv[d + 0];
        float f1 = q.y - xv[d + 1];
        float f2 = q.z - xv[d + 2];
        float f3 = q.w - xv[d + 3];
        acc = fmaf(f0, f0, acc);
        acc = fmaf(f1, f1, acc);
        acc = fmaf(f2, f2, acc);
        acc = fmaf(f3, f3, acc);
        qp[(d + 0) * 1024] = q.x;
        qp[(d + 1) * 1024] = q.y;
        qp[(d + 2) * 1024] = q.z;
        qp[(d + 3) * 1024] = q.w;
    }
    out_idx[n] = (float)bi;

    // wave-internal loss reduce
    #pragma unroll
    for (int off = 32; off > 0; off >>= 1) acc += __shfl_down(acc, off);
    if (lane == 0) partial[blockIdx.x] = acc;
}

// ---------------- kernel 3: finalize loss over 1024 partials ----------------
__global__ __launch_bounds__(256) void vq_loss(const float* __restrict__ partial,
                                               float* __restrict__ loss) {
    const int t = threadIdx.x;
    float v = (partial[t] + partial[t + 256]) + (partial[t + 512] + partial[t + 768]);
    #pragma unroll
    for (int off = 32; off > 0; off >>= 1) v += __shfl_down(v, off);
    __shared__ float red[4];
    if ((t & 63) == 0) red[t >> 6] = v;
    __syncthreads();
    if (t == 0)
        loss[0] = 1.25f * ((red[0] + red[1]) + (red[2] + red[3])) / (float)Q_ELEMS;
}

extern "C" void kernel_launch(void* const* d_in, const int* in_sizes, int n_in,
                              void* d_out, int out_size, void* d_ws, size_t ws_size,
                              hipStream_t stream) {
    const float* x   = (const float*)d_in[0];   // [64,64,32,32] NCHW
    const float* emb = (const float*)d_in[1];   // [512,64]

    float* out_q    = (float*)d_out;                // [4194304]
    float* out_loss = (float*)d_out + Q_ELEMS;      // [1]
    float* out_idx  = (float*)d_out + Q_ELEMS + 1;  // [65536] as float

    float* t2      = (float*)d_ws;       // 512 floats
    float* partial = t2 + K_EMB;         // 1024 floats

    vq_prep<<<2, 256, 0, stream>>>(emb, t2);
    vq_main<<<NBLK, 1024, 0, stream>>>(x, emb, t2, out_q, out_idx, partial);
    vq_loss<<<1, 256, 0, stream>>>(partial, out_loss);
}

// Round 12
// 91.395 us; speedup vs baseline: 1.2678x; 1.1535x over previous
//
#include <hip/hip_runtime.h>
#include <float.h>

// VectorQuantizer on MI355X — bit-exact numpy-f32 replication (R4-proven numerics).
//
// Ladder: R4 274us (1 wave/SIMD) -> R7 97us (s_load e-rows + 4 waves/SIMD) ->
// R8/R9/R10/R11 all ~96-113us (waves_per_eu, LDS-x, contiguous-xt, 16-wave
// blocks: no gain). Invariant: VALU-busy-time ~60us at 57-63% duty.
// R11 failure analysis: 1024-thread gangs fragment wave slots (occ 39.7% not
// 100%), 32-code k-range under-amortizes the cold-s_load prologue, 15/16 waves
// idle during epilogue.
// R12: 512-thread blocks / 8-wave K-split (64 codes per wave) — 4 blocks/CU x
// 8 waves = 32 waves/CU target, half the gang size of R11, R7's inner loop
// byte-for-byte. Merge ascending-wave strict '<' == ascending-k first-min.
#pragma clang fp contract(off)

#define K_EMB   512
#define D_EMB   64
#define Q_ELEMS 4194304   // 64 * 64 * 32 * 32
#define NBLK    1024      // 64 pixels per block, 8 waves split K

// numpy pairwise_sum order for n=64 contiguous f32, summing PRE-ROUNDED squares.
__device__ __forceinline__ float np_sumsq64(const float* __restrict__ v) {
    float r[8];
    #pragma unroll
    for (int j = 0; j < 8; ++j) r[j] = v[j] * v[j];
    #pragma unroll
    for (int i = 8; i < 64; i += 8) {
        #pragma unroll
        for (int j = 0; j < 8; ++j) {
            float s = v[i + j] * v[i + j];
            r[j] = r[j] + s;
        }
    }
    return ((r[0] + r[1]) + (r[2] + r[3])) + ((r[4] + r[5]) + (r[6] + r[7]));
}

// ---------------- kernel 1: t2[k] = np-f32 sum(emb_k^2) ----------------
__global__ __launch_bounds__(256) void vq_prep(const float* __restrict__ emb,
                                               float* __restrict__ t2) {
    int k = blockIdx.x * 256 + threadIdx.x;
    if (k < K_EMB) {
        const float* ep = emb + (k << 6);
        float e[D_EMB];
        #pragma unroll
        for (int j = 0; j < D_EMB; ++j) e[j] = ep[j];
        t2[k] = np_sumsq64(e);
    }
}

// ---------------- kernel 2: main VQ ----------------
__global__ __launch_bounds__(512) void vq_main(const float* __restrict__ x,
                                               const float* __restrict__ emb,
                                               const float* __restrict__ t2,
                                               float* __restrict__ out_q,
                                               float* __restrict__ out_idx,
                                               float* __restrict__ partial) {
    const int tid  = threadIdx.x;
    const int lane = tid & 63;
    // PROVABLY wave-uniform wave id -> e addresses stay scalar -> s_load (R7)
    const int wave = __builtin_amdgcn_readfirstlane(tid >> 6);   // 0..7

    const int n  = blockIdx.x * 64 + lane;           // pixel index
    const int b  = n >> 10;
    const int hw = n & 1023;
    const float* __restrict__ xp = x + b * 65536 + hw;

    // x[n, 0..63]; allocator remats these in the k-loop (proven harmless R10)
    float xv[D_EMB];
    #pragma unroll
    for (int d = 0; d < D_EMB; ++d) xv[d] = xp[d * 1024];

    const float t1 = np_sumsq64(xv);   // numpy tree, f32 (same in all 8 waves)

    float best = FLT_MAX;
    int   bi   = 0;
    const int k0 = wave << 6;          // this wave's 64-code range (uniform)
    for (int kk = 0; kk < 64; kk += 4) {
        const int k = k0 + kk;
        const float* __restrict__ e0 = emb + ((k + 0) << 6);  // uniform -> s_load
        const float* __restrict__ e1 = emb + ((k + 1) << 6);
        const float* __restrict__ e2 = emb + ((k + 2) << 6);
        const float* __restrict__ e3 = emb + ((k + 3) << 6);
        float a0 = 0.f, a1 = 0.f, a2 = 0.f, a3 = 0.f;
        #pragma unroll
        for (int d = 0; d < D_EMB; ++d) {
            a0 = fmaf(xv[d], e0[d], a0);   // BLAS chain: one fma rounding per step
            a1 = fmaf(xv[d], e1[d], a1);
            a2 = fmaf(xv[d], e2[d], a2);
            a3 = fmaf(xv[d], e3[d], a3);
        }
        // dist = fl32( fl32(t1+t2) - 2*d ): 2*d exact -> fmaf = identical rounding
        float X0 = t1 + t2[k + 0];
        float X1 = t1 + t2[k + 1];
        float X2 = t1 + t2[k + 2];
        float X3 = t1 + t2[k + 3];
        float d0 = fmaf(-2.f, a0, X0);
        float d1 = fmaf(-2.f, a1, X1);
        float d2 = fmaf(-2.f, a2, X2);
        float d3 = fmaf(-2.f, a3, X3);
        if (d0 < best) { best = d0; bi = k + 0; }   // strict <: first-min tiebreak
        if (d1 < best) { best = d1; bi = k + 1; }
        if (d2 < best) { best = d2; bi = k + 2; }
        if (d3 < best) { best = d3; bi = k + 3; }
    }

    // cross-wave argmin merge (ascending wave == ascending k; strict <)
    __shared__ float s_best[8][64];
    __shared__ int   s_bi[8][64];
    s_best[wave][lane] = best;
    s_bi[wave][lane]   = bi;
    __syncthreads();
    if (wave != 0) return;

    #pragma unroll
    for (int w = 1; w < 8; ++w) {
        float dw = s_best[w][lane];
        if (dw < best) { best = dw; bi = s_bi[w][lane]; }
    }

    // epilogue (wave 0): gather winning embedding, write quantized, loss partial
    const float4* __restrict__ eq = (const float4*)(emb + (bi << 6));
    float* __restrict__ qp = out_q + b * 65536 + hw;
    float acc = 0.f;
    #pragma unroll
    for (int j = 0; j < 16; ++j) {
        float4 q = eq[j];
        const int d = j * 4;
        float f0 = q.x - xv[d + 0];
        float f1 = q.y - xv[d + 1];
        float f2 = q.z - xv[d + 2];
        float f3 = q.w - xv[d + 3];
        acc = fmaf(f0, f0, acc);
        acc = fmaf(f1, f1, acc);
        acc = fmaf(f2, f2, acc);
        acc = fmaf(f3, f3, acc);
        qp[(d + 0) * 1024] = q.x;
        qp[(d + 1) * 1024] = q.y;
        qp[(d + 2) * 1024] = q.z;
        qp[(d + 3) * 1024] = q.w;
    }
    out_idx[n] = (float)bi;

    // wave-internal loss reduce
    #pragma unroll
    for (int off = 32; off > 0; off >>= 1) acc += __shfl_down(acc, off);
    if (lane == 0) partial[blockIdx.x] = acc;
}

// ---------------- kernel 3: finalize loss over 1024 partials ----------------
__global__ __launch_bounds__(256) void vq_loss(const float* __restrict__ partial,
                                               float* __restrict__ loss) {
    const int t = threadIdx.x;
    float v = (partial[t] + partial[t + 256]) + (partial[t + 512] + partial[t + 768]);
    #pragma unroll
    for (int off = 32; off > 0; off >>= 1) v += __shfl_down(v, off);
    __shared__ float red[4];
    if ((t & 63) == 0) red[t >> 6] = v;
    __syncthreads();
    if (t == 0)
        loss[0] = 1.25f * ((red[0] + red[1]) + (red[2] + red[3])) / (float)Q_ELEMS;
}

extern "C" void kernel_launch(void* const* d_in, const int* in_sizes, int n_in,
                              void* d_out, int out_size, void* d_ws, size_t ws_size,
                              hipStream_t stream) {
    const float* x   = (const float*)d_in[0];   // [64,64,32,32] NCHW
    const float* emb = (const float*)d_in[1];   // [512,64]

    float* out_q    = (float*)d_out;                // [4194304]
    float* out_loss = (float*)d_out + Q_ELEMS;      // [1]
    float* out_idx  = (float*)d_out + Q_ELEMS + 1;  // [65536] as float

    float* t2      = (float*)d_ws;       // 512 floats
    float* partial = t2 + K_EMB;         // 1024 floats

    vq_prep<<<2, 256, 0, stream>>>(emb, t2);
    vq_main<<<NBLK, 512, 0, stream>>>(x, emb, t2, out_q, out_idx, partial);
    vq_loss<<<1, 256, 0, stream>>>(partial, out_loss);
}

// Round 13
// 87.626 us; speedup vs baseline: 1.3224x; 1.0430x over previous
//
#include <hip/hip_runtime.h>
#include <float.h>

// VectorQuantizer on MI355X — f16 dot2 screen + windowed bit-exact np-f32 rescue.
//
// R4-R12: bit-exact np-f32 everywhere -> all configs pin at ~96us with VALU-busy
// ~60us (instruction-count bound, 2.2x fma floor; occupancy/data-path moves null).
// R13: halve the hot stream with v_dot2_f32_f16 (2 MAC/instr) as a SCREEN:
//   u = 512*e (exact pow2 scale; f16, no subnormals), s_k = 512*t2_k - 2*x_f16.u_k
//   = 512*(||e||^2 - 2x.e) + eps, |eps| <= ~0.07 scaled (worst pixel, incl f16
//   store round 0.016) while np-f32 rounding slop is 512*3.2e-5 = 0.016.
//   Window W=0.5 (>4x margin): every np-f32 argmin provably lands in the
//   candidate set {k: s_k_f16 < min_global(s)+W}; expected ~1.2 cands/pixel.
// Phase2 re-reads f16 screen dists from LDS and runs the R4-proven EXACT np-f32
// chain (fmaf sequential, X=t1+t2, fmaf(-2,a,X)) only on candidates; merge
// ascending k/wave with strict '<' == numpy first-min tiebreak.
#pragma clang fp contract(off)

#define K_EMB   512
#define D_EMB   64
#define Q_ELEMS 4194304   // 64 * 64 * 32 * 32
#define NBLK    1024      // 64 pixels per block, 8 waves split K
#define W_SCR   0.5f      // candidate window, scaled units (512x)

typedef _Float16 half2_t __attribute__((ext_vector_type(2)));

#if __has_builtin(__builtin_amdgcn_fdot2)
__device__ __forceinline__ float fdot2(half2_t a, half2_t b, float c) {
    return __builtin_amdgcn_fdot2(a, b, c, false);
}
#else
__device__ __forceinline__ float fdot2(half2_t a, half2_t b, float c) {
    return fmaf((float)a[0], (float)b[0], fmaf((float)a[1], (float)b[1], c));
}
#endif

// numpy pairwise_sum order for n=64 contiguous f32, summing PRE-ROUNDED squares.
__device__ __forceinline__ float np_sumsq64(const float* __restrict__ v) {
    float r[8];
    #pragma unroll
    for (int j = 0; j < 8; ++j) r[j] = v[j] * v[j];
    #pragma unroll
    for (int i = 8; i < 64; i += 8) {
        #pragma unroll
        for (int j = 0; j < 8; ++j) {
            float s = v[i + j] * v[i + j];
            r[j] = r[j] + s;
        }
    }
    return ((r[0] + r[1]) + (r[2] + r[3])) + ((r[4] + r[5]) + (r[6] + r[7]));
}

// ---------------- kernel 1: t2 (np-exact), 512*t2, u=512e in f16 ----------------
__global__ __launch_bounds__(256) void vq_prep(const float* __restrict__ emb,
                                               float* __restrict__ t2,
                                               float* __restrict__ t2s512,
                                               half2_t* __restrict__ embh) {
    int k = blockIdx.x * 256 + threadIdx.x;
    if (k < K_EMB) {
        const float* ep = emb + (k << 6);
        float e[D_EMB];
        #pragma unroll
        for (int j = 0; j < D_EMB; ++j) e[j] = ep[j];
        float s = np_sumsq64(e);
        t2[k]     = s;
        t2s512[k] = 512.0f * s;                      // pow2 scale: exact
        #pragma unroll
        for (int j = 0; j < 32; ++j) {
            half2_t u;
            u[0] = (_Float16)(512.0f * e[2 * j + 0]);  // exact scale, RN cvt
            u[1] = (_Float16)(512.0f * e[2 * j + 1]);
            embh[k * 32 + j] = u;
        }
    }
}

// ---------------- kernel 2: main VQ (screen + rescue) ----------------
__global__ __launch_bounds__(512) void vq_main(const float* __restrict__ x,
                                               const float* __restrict__ emb,
                                               const float* __restrict__ t2,
                                               const float* __restrict__ t2s512,
                                               const half2_t* __restrict__ embh,
                                               float* __restrict__ out_q,
                                               float* __restrict__ out_idx,
                                               float* __restrict__ partial) {
    const int tid  = threadIdx.x;
    const int lane = tid & 63;
    const int wave = __builtin_amdgcn_readfirstlane(tid >> 6);   // 0..7, uniform

    const int n  = blockIdx.x * 64 + lane;           // pixel index
    const int b  = n >> 10;
    const int hw = n & 1023;
    const float* __restrict__ xp = x + b * 65536 + hw;

    float xv[D_EMB];
    #pragma unroll
    for (int d = 0; d < D_EMB; ++d) xv[d] = xp[d * 1024];

    const float t1 = np_sumsq64(xv);                 // np-exact f32

    half2_t xh[32];                                  // x in f16 (RN scalar cvts)
    #pragma unroll
    for (int j = 0; j < 32; ++j) {
        half2_t h;
        h[0] = (_Float16)xv[2 * j + 0];
        h[1] = (_Float16)xv[2 * j + 1];
        xh[j] = h;
    }

    __shared__ _Float16 sd[8][64][66];               // 66-pad: conflict-free rows
    __shared__ float    bsm[8][64];
    __shared__ float    s_bnp[8][64];
    __shared__ int      s_bk[8][64];

    // ---- phase 1: f16 dot2 screen over this wave's 64 codes ----
    float bs = FLT_MAX;
    const int k0 = wave << 6;
    for (int kk = 0; kk < 64; kk += 4) {
        const int k = k0 + kk;
        const half2_t* __restrict__ u0 = embh + (k + 0) * 32;   // uniform -> s_load
        const half2_t* __restrict__ u1 = embh + (k + 1) * 32;
        const half2_t* __restrict__ u2 = embh + (k + 2) * 32;
        const half2_t* __restrict__ u3 = embh + (k + 3) * 32;
        float a0 = 0.f, a1 = 0.f, a2 = 0.f, a3 = 0.f;
        #pragma unroll
        for (int j = 0; j < 32; ++j) {
            a0 = fdot2(xh[j], u0[j], a0);
            a1 = fdot2(xh[j], u1[j], a1);
            a2 = fdot2(xh[j], u2[j], a2);
            a3 = fdot2(xh[j], u3[j], a3);
        }
        const float s0 = fmaf(-2.f, a0, t2s512[k + 0]);   // scaled screen dist
        const float s1 = fmaf(-2.f, a1, t2s512[k + 1]);
        const float s2 = fmaf(-2.f, a2, t2s512[k + 2]);
        const float s3 = fmaf(-2.f, a3, t2s512[k + 3]);
        half2_t p01, p23;
        p01[0] = (_Float16)s0; p01[1] = (_Float16)s1;
        p23[0] = (_Float16)s2; p23[1] = (_Float16)s3;
        *(half2_t*)&sd[wave][lane][kk + 0] = p01;
        *(half2_t*)&sd[wave][lane][kk + 2] = p23;
        bs = fminf(bs, fminf(fminf(s0, s1), fminf(s2, s3)));
    }
    bsm[wave][lane] = bs;
    __syncthreads();

    float bsg = bsm[0][lane];
    #pragma unroll
    for (int w = 1; w < 8; ++w) bsg = fminf(bsg, bsm[w][lane]);
    const float thr = bsg + W_SCR;

    // ---- phase 2: rescue — exact np-f32 chain for screen candidates ----
    float bnp = FLT_MAX;
    int   bk  = 0;
    for (int kk = 0; kk < 64; kk += 2) {
        half2_t p = *(const half2_t*)&sd[wave][lane][kk];
        const float s0 = (float)p[0];
        const float s1 = (float)p[1];
        if (s0 < thr) {
            const int k = k0 + kk;
            const float* __restrict__ ep = emb + (k << 6);
            float a = 0.f;
            #pragma unroll
            for (int d = 0; d < D_EMB; ++d) a = fmaf(xv[d], ep[d], a);
            float X = t1 + t2[k];
            float dnp = fmaf(-2.f, a, X);
            if (dnp < bnp) { bnp = dnp; bk = k; }
        }
        if (s1 < thr) {
            const int k = k0 + kk + 1;
            const float* __restrict__ ep = emb + (k << 6);
            float a = 0.f;
            #pragma unroll
            for (int d = 0; d < D_EMB; ++d) a = fmaf(xv[d], ep[d], a);
            float X = t1 + t2[k];
            float dnp = fmaf(-2.f, a, X);
            if (dnp < bnp) { bnp = dnp; bk = k; }
        }
    }

    // cross-wave merge of np-exact winners (ascending wave == ascending k)
    s_bnp[wave][lane] = bnp;
    s_bk[wave][lane]  = bk;
    __syncthreads();
    if (wave != 0) return;

    float best = s_bnp[0][lane];
    int   bi   = s_bk[0][lane];
    #pragma unroll
    for (int w = 1; w < 8; ++w) {
        float dw = s_bnp[w][lane];
        if (dw < best) { best = dw; bi = s_bk[w][lane]; }
    }

    // epilogue (wave 0): gather winning embedding, write quantized, loss partial
    const float4* __restrict__ eq = (const float4*)(emb + (bi << 6));
    float* __restrict__ qp = out_q + b * 65536 + hw;
    float acc = 0.f;
    #pragma unroll
    for (int j = 0; j < 16; ++j) {
        float4 q = eq[j];
        const int d = j * 4;
        float f0 = q.x - xv[d + 0];
        float f1 = q.y - xv[d + 1];
        float f2 = q.z - xv[d + 2];
        float f3 = q.w - xv[d + 3];
        acc = fmaf(f0, f0, acc);
        acc = fmaf(f1, f1, acc);
        acc = fmaf(f2, f2, acc);
        acc = fmaf(f3, f3, acc);
        qp[(d + 0) * 1024] = q.x;
        qp[(d + 1) * 1024] = q.y;
        qp[(d + 2) * 1024] = q.z;
        qp[(d + 3) * 1024] = q.w;
    }
    out_idx[n] = (float)bi;

    #pragma unroll
    for (int off = 32; off > 0; off >>= 1) acc += __shfl_down(acc, off);
    if (lane == 0) partial[blockIdx.x] = acc;
}

// ---------------- kernel 3: finalize loss over 1024 partials ----------------
__global__ __launch_bounds__(256) void vq_loss(const float* __restrict__ partial,
                                               float* __restrict__ loss) {
    const int t = threadIdx.x;
    float v = (partial[t] + partial[t + 256]) + (partial[t + 512] + partial[t + 768]);
    #pragma unroll
    for (int off = 32; off > 0; off >>= 1) v += __shfl_down(v, off);
    __shared__ float red[4];
    if ((t & 63) == 0) red[t >> 6] = v;
    __syncthreads();
    if (t == 0)
        loss[0] = 1.25f * ((red[0] + red[1]) + (red[2] + red[3])) / (float)Q_ELEMS;
}

extern "C" void kernel_launch(void* const* d_in, const int* in_sizes, int n_in,
                              void* d_out, int out_size, void* d_ws, size_t ws_size,
                              hipStream_t stream) {
    const float* x   = (const float*)d_in[0];   // [64,64,32,32] NCHW
    const float* emb = (const float*)d_in[1];   // [512,64]

    float* out_q    = (float*)d_out;                // [4194304]
    float* out_loss = (float*)d_out + Q_ELEMS;      // [1]
    float* out_idx  = (float*)d_out + Q_ELEMS + 1;  // [65536] as float

    float*   t2      = (float*)d_ws;                // 512
    float*   t2s512  = t2 + K_EMB;                  // 512
    float*   partial = t2s512 + K_EMB;              // 1024
    half2_t* embh    = (half2_t*)(partial + 1024);  // 512*32 half2 = 64KB

    vq_prep<<<2, 256, 0, stream>>>(emb, t2, t2s512, embh);
    vq_main<<<NBLK, 512, 0, stream>>>(x, emb, t2, t2s512, embh,
                                      out_q, out_idx, partial);
    vq_loss<<<1, 256, 0, stream>>>(partial, out_loss);
}